// Round 7
// baseline (239.514 us; speedup 1.0000x reference)
//
#include <hip/hip_runtime.h>

#define B 8
#define N 2048
#define D 1024
#define SC 64          // fine chunks along i (records)
#define LC (N / SC)    // 32 rows per fine chunk
#define C2 16          // coarse chunks in k_so
#define LR (N / C2)    // 128 rows per coarse chunk
#define DQ 4           // D-quarters in k_so
#define COLS (D / DQ)  // 256 cols per k_so block
#define M 6            // Taylor terms

// ws layout (floats):
//   kq   @ 0     : 2*B*N = 32768   (k then q)
//   part @ 65536 : B*SC*M*D = 3145728 floats (~12.6 MB)

// ---------------------------------------------------------------------------
// D1: fused projection + fine-chunk moments. Block = (b, sc), 512 threads.
//     8 waves x 4 rows each (R6 had 4 waves x 8 rows: half the per-wave
//     serialization, 2x the waves/CU). Block is self-sufficient: projects
//     its own 32 rows (k in LDS; k/q also to kq for D2), then accumulates
//     the record. No inter-block dependency, no sync, no spin.
__global__ __launch_bounds__(512, 4) void k_pp(const float* __restrict__ x,
                                               const float* __restrict__ f,
                                               const float* __restrict__ wk,
                                               const float* __restrict__ wq,
                                               float* __restrict__ kq,
                                               float* __restrict__ part) {
    const int sc   = blockIdx.x & (SC - 1);
    const int b    = blockIdx.x >> 6;
    const int tid  = threadIdx.x;
    const int wave = tid >> 6;                         // 0..7
    const int lane = tid & 63;

    __shared__ float sk[LC];

    // ---- projection: 4 rows per wave (same op order as proven k_proj)
    {
        const float4* wk4 = (const float4*)wk;
        const float4* wq4 = (const float4*)wq;
        float4 kw[4], qw[4];
#pragma unroll
        for (int t = 0; t < 4; ++t) { kw[t] = wk4[t * 64 + lane]; qw[t] = wq4[t * 64 + lane]; }
#pragma unroll
        for (int r = 0; r < 4; ++r) {
            const int rl  = wave * 4 + r;              // local row 0..31
            const int row = b * N + sc * LC + rl;
            const float4* xr = (const float4*)(x + (size_t)row * D);
            float ak = 0.f, aq = 0.f;
#pragma unroll
            for (int t = 0; t < 4; ++t) {
                float4 xv = xr[t * 64 + lane];
                ak += xv.x * kw[t].x + xv.y * kw[t].y + xv.z * kw[t].z + xv.w * kw[t].w;
                aq += xv.x * qw[t].x + xv.y * qw[t].y + xv.z * qw[t].z + xv.w * qw[t].w;
            }
#pragma unroll
            for (int off = 32; off > 0; off >>= 1) {
                ak += __shfl_down(ak, off, 64);
                aq += __shfl_down(aq, off, 64);
            }
            if (lane == 0) {
                sk[rl] = ak;                           // local use (moments)
                kq[row] = ak;                          // D2: scalar prefix
                kq[B * N + row] = aq;                  // D2: Horner coeff
            }
        }
    }
    __syncthreads();

    // ---- fine-chunk moments: thread owns cols (2*tid, 2*tid+1).
    //      Row-serial accumulation: record content identical to k_part.
    const float2* fb = (const float2*)(f + (size_t)(b * N + sc * LC) * D) + tid;
    float2 s[M];
#pragma unroll
    for (int m = 0; m < M; ++m) s[m] = make_float2(0.f, 0.f);
#pragma unroll 8
    for (int i = 0; i < LC; ++i) {
        float2 ff = fb[i * (D / 2)];
        float  kk = sk[i];
        float  w  = (kk != 0.0f) ? 1.0f : 0.0f;
        s[0].x += w * ff.x; s[0].y += w * ff.y;
        float kp = kk;
#pragma unroll
        for (int m = 1; m < M; ++m) {
            s[m].x += kp * ff.x; s[m].y += kp * ff.y;
            kp *= kk;
        }
    }
    float2* pb = (float2*)(part + (size_t)(b * SC + sc) * M * D) + tid;
#pragma unroll
    for (int m = 0; m < M; ++m) pb[m * (D / 2)] = s[m];
}

// ---------------------------------------------------------------------------
// D2: fused scan + output. Block = (b, c2, dq): rows [c2*128, +128),
//     cols [dq*256, +256). The vector exclusive prefix is the forward-
//     ordered sum of fine records p < 4*c2 for this col slice (records are
//     complete: previous dispatch) — same association as the in-place scan.
//     Wave 0 recomputes the scalar prefix (R3 k_out verbatim, lane = fine
//     chunk, Kogge-Stone, taken at lane 4*c2) while waves 1-3 do lookback.
__global__ __launch_bounds__(256, 4) void k_so(const float* __restrict__ kq,
                                               const float* __restrict__ f,
                                               const float* __restrict__ part,
                                               float* __restrict__ out) {
    const int dq  = blockIdx.x & (DQ - 1);
    const int c   = (blockIdx.x >> 2) & (C2 - 1);
    const int b   = blockIdx.x >> 6;
    const int tid = threadIdx.x;
    const int col = dq * COLS + tid;

    __shared__ float sk[LR];
    __shared__ float sq[LR];
    __shared__ float sT[M];

    // sk/sq for this block's 128 rows (not read until after the barrier)
    if (tid < 128) sk[tid]       = kq[b * N + c * LR + tid];
    else           sq[tid - 128] = kq[B * N + b * N + c * LR + (tid - 128)];

    // ---- wave 0: scalar exclusive prefix at fine chunk 4*c (R3 verbatim)
    if (tid < 64) {
        float tm[M] = {0.f, 0.f, 0.f, 0.f, 0.f, 0.f};
        const float* kb = kq + b * N + tid * LC;
#pragma unroll
        for (int i = 0; i < LC; ++i) {
            float kk = kb[i];
            tm[0] += (kk != 0.0f) ? 1.0f : 0.0f;
            float kp = kk;
#pragma unroll
            for (int m = 1; m < M; ++m) { tm[m] += kp; kp *= kk; }
        }
#pragma unroll
        for (int m = 0; m < M; ++m) {
            float v = tm[m];
            const float orig = v;
#pragma unroll
            for (int off = 1; off < 64; off <<= 1) {
                float nv = __shfl_up(v, off, 64);
                if (tid >= off) v += nv;
            }
            if (tid == 4 * c) sT[m] = v - orig;        // exclusive @ fine 4c
        }
    }

    // ---- bounded lookback: forward order over fine records (all threads)
    float run[M] = {0.f, 0.f, 0.f, 0.f, 0.f, 0.f};
    {
        const float* pbase = part + (size_t)(b * SC) * M * D + col;
#pragma unroll 1
        for (int p = 0; p < 4 * c; ++p) {
            const float* rp = pbase + (size_t)p * (M * D);
#pragma unroll
            for (int m = 0; m < M; ++m) run[m] += rp[m * D];
        }
    }
    __syncthreads();                                   // sT, sk, sq ready

    float t[M];
#pragma unroll
    for (int m = 0; m < M; ++m) t[m] = sT[m];

    // ---- local scan + Horner + store (row-serial, 128 rows)
    const float* fb = f + (size_t)(b * N + c * LR) * D + col;
    float*       ob = out + (size_t)(b * N + c * LR) * D + col;
#pragma unroll 4
    for (int i = 0; i < LR; ++i) {
        float ff = fb[(size_t)i * D];
        float kk = sk[i];
        float qq = sq[i];
        float w  = (kk != 0.0f) ? 1.0f : 0.0f;
        t[0] += w;
        run[0] += w * ff;
        float kp = kk;
#pragma unroll
        for (int m = 1; m < M; ++m) {
            t[m] += kp;
            run[m] += kp * ff;
            kp *= kk;
        }
        const float cj = qq * 0.03125f;
        const float g2 = cj * 0.5f;
        const float g3 = cj * (1.0f / 3.0f);
        const float g4 = cj * 0.25f;
        const float g5 = cj * 0.2f;
        float Z = ((((t[5] * g5 + t[4]) * g4 + t[3]) * g3 + t[2]) * g2 + t[1]) * cj + t[0];
        float rz = __builtin_amdgcn_rcpf(Z);
        ob[(size_t)i * D] =
            (((((run[5] * g5 + run[4]) * g4 + run[3]) * g3 + run[2]) * g2 + run[1]) * cj + run[0]) * rz;
    }
}

// ---------------------------------------------------------------------------
extern "C" void kernel_launch(void* const* d_in, const int* in_sizes, int n_in,
                              void* d_out, int out_size, void* d_ws, size_t ws_size,
                              hipStream_t stream) {
    (void)in_sizes; (void)n_in; (void)out_size; (void)ws_size;
    const float* x  = (const float*)d_in[0];
    const float* f  = (const float*)d_in[1];
    const float* wk = (const float*)d_in[2];
    const float* wq = (const float*)d_in[3];
    float* out = (float*)d_out;
    float* ws  = (float*)d_ws;

    float* kq   = ws;
    float* part = ws + 65536;

    hipLaunchKernelGGL(k_pp, dim3(B * SC),       dim3(512), 0, stream, x, f, wk, wq, kq, part);
    hipLaunchKernelGGL(k_so, dim3(B * C2 * DQ),  dim3(256), 0, stream, kq, f, part, out);
}